// Round 7
// baseline (277.889 us; speedup 1.0000x reference)
//
#include <hip/hip_runtime.h>
#include <hip/hip_bf16.h>

// LossUnsupervised v6 — swapped-operand MFMA, single-bf16 A, 8 waves/block.
// prep (32x256): m' = m/s1^2 -> bf16 A-frag order (ws); p2 = (1+|m|^2)/s1^2.
// fused_main (2048x512, 8 waves): block owns 128 rows (8 chunks of 16);
//   wave w holds centers [32w,32w+32) of m' in 32 VGPRs (2 tiles x 4 ksteps).
//   D = m'.x^T puts a row's logits lane-local: softmax partials (S,T) are
//   in-register sums + 2 shfl_xor (row max fixed at 0, logits <= 0).
//   Partials -> 8KB LDS, ONE barrier, combine, block sum. Single-bf16 x:
//   per-row entropy error ~3e-5 random, cancels to ~1e-7 in the 262k-mean.
// finalize (1x1024): blocksum reduce (double) + inter-center entropy.

#define N_ROWS 262144

typedef __attribute__((ext_vector_type(8))) short bf16x8;
typedef __attribute__((ext_vector_type(4))) float f32x4;
typedef __attribute__((ext_vector_type(4))) unsigned short u16x4;

__device__ __forceinline__ unsigned short bf16_rne(float x) {
    unsigned int u = __float_as_uint(x);
    u += 0x7FFFu + ((u >> 16) & 1u);
    return (unsigned short)(u >> 16);
}

// 8 floats -> bf16 (cvt_pk pairs), n2 += sum of squares
__device__ __forceinline__ void cvt8h(float4 a, float4 b, bf16x8& hi, float& n2) {
    float xs[8] = {a.x, a.y, a.z, a.w, b.x, b.y, b.z, b.w};
    unsigned hp[4];
    #pragma unroll
    for (int p = 0; p < 4; ++p) {
        float e = xs[2*p], o = xs[2*p+1];
        n2 = __builtin_fmaf(e, e, n2);
        n2 = __builtin_fmaf(o, o, n2);
        __hip_bfloat162 hv = __float22bfloat162_rn(make_float2(e, o));
        hp[p] = *reinterpret_cast<unsigned*>(&hv);
    }
    hi = *reinterpret_cast<bf16x8*>(hp);
}

__global__ __launch_bounds__(256) void prep(
    const float* __restrict__ m, const float* __restrict__ s1,
    unsigned short* __restrict__ mhi_g, float* __restrict__ p2_g)
{
    const int t    = threadIdx.x;
    const int lane = t & 63;
    const int k    = blockIdx.x * 8 + (t >> 5);   // center index
    const int f4   = t & 31;                      // float4 within row
    float4 v = reinterpret_cast<const float4*>(m)[k * 32 + f4];
    float pn = v.x*v.x + v.y*v.y + v.z*v.z + v.w*v.w;
    #pragma unroll
    for (int msk = 1; msk <= 16; msk <<= 1) pn += __shfl_xor(pn, msk);
    float sv  = s1[k];
    float isv = 1.0f / (sv * sv);
    if ((lane & 31) == 0) p2_g[k] = (1.0f + pn) * isv;   // (1+|m|^2)/s^2
    const int f0 = f4 << 2;
    const int c = k >> 4, n = k & 15, s = f0 >> 5, blk = (f0 >> 3) & 3, i0 = f0 & 7;
    const int elem = ((c * 4 + s) * 64 + blk * 16 + n) * 8 + i0;
    float xs[4] = {v.x * isv, v.y * isv, v.z * isv, v.w * isv};  // m' = m/s^2
    u16x4 hh;
    #pragma unroll
    for (int q = 0; q < 4; ++q) hh[q] = bf16_rne(xs[q]);
    *(u16x4*)(mhi_g + elem) = hh;
}

__global__ __launch_bounds__(512, 4) void fused_main(
    const float* __restrict__ x, const unsigned short* __restrict__ mhi_g,
    const float* __restrict__ p2_g, float* __restrict__ blocksum)
{
    __shared__ float p2s[256];
    __shared__ float part[8][16][8][2];   // [chunk][row16][wave][S,T]
    __shared__ float entred[8];

    const int tid  = threadIdx.x;
    const int lane = tid & 63;
    const int w    = tid >> 6;        // wave 0..7: centers [32w, 32w+32)
    const int rw   = lane & 15;       // x-row within chunk (C col)
    const int blkl = lane >> 4;       // k-block / C row-group

    if (tid < 256) p2s[tid] = p2_g[tid];

    // wave's B: 2 center-tiles x 4 k-steps, 32 VGPR, stationary
    bf16x8 MB[8];
    #pragma unroll
    for (int tt = 0; tt < 2; ++tt)
        #pragma unroll
        for (int s = 0; s < 4; ++s)
            MB[tt*4+s] = *(const bf16x8*)(mhi_g + (((2*w + tt)*4 + s)*64 + lane)*8);

    __syncthreads();   // p2s ready

    const float* xb = x + (size_t)(blockIdx.x * 128 + rw) * 128 + blkl * 8;

    // 3-deep circular prefetch over flattened ksteps g = t*4 + s
    float4 PA[3], PB[3];
    #pragma unroll
    for (int g = 0; g < 3; ++g) {
        PA[g] = *(const float4*)(xb + g * 32);
        PB[g] = *(const float4*)(xb + g * 32 + 4);
    }

    f32x4 acc[2];
    float n2 = 0.0f;

    #pragma unroll
    for (int g = 0; g < 32; ++g) {
        const int s = g & 3;             // k-step within chunk
        const int slot = g % 3;
        if (s == 0) {
            acc[0] = f32x4{0.f, 0.f, 0.f, 0.f};
            acc[1] = f32x4{0.f, 0.f, 0.f, 0.f};
            n2 = 0.0f;
        }
        bf16x8 ah;
        cvt8h(PA[slot], PB[slot], ah, n2);
        if (g + 3 < 32) {   // refill this slot with kstep g+3
            const int g2 = g + 3;
            const float* p = xb + (size_t)(g2 >> 2) * 2048 + (g2 & 3) * 32;
            PA[slot] = *(const float4*)(p);
            PB[slot] = *(const float4*)(p + 4);
        }
        acc[0] = __builtin_amdgcn_mfma_f32_16x16x32_bf16(MB[s],     ah, acc[0], 0, 0, 0);
        acc[1] = __builtin_amdgcn_mfma_f32_16x16x32_bf16(MB[4 + s], ah, acc[1], 0, 0, 0);
        if (s == 3) {
            // ---- chunk epilogue: lane-local softmax partials over 32 centers ----
            const int t = g >> 2;
            float nn = n2;
            nn += __shfl_xor(nn, 16);
            nn += __shfl_xor(nn, 32);        // all 4 lanes of row rw share nn
            float ar = 2.0f * __frsqrt_rn(fmaxf(nn, 1e-24f));
            float S = 0.f, T = 0.f;
            #pragma unroll
            for (int tt = 0; tt < 2; ++tt) {
                f32x4 p2v = *(const f32x4*)&p2s[(2*w + tt)*16 + blkl*4];
                #pragma unroll
                for (int r = 0; r < 4; ++r) {
                    float l = fminf(__builtin_fmaf(ar, acc[tt][r], -p2v[r]), 0.0f);
                    float e = __expf(l);
                    S += e;
                    T = __builtin_fmaf(l, e, T);
                }
            }
            S += __shfl_xor(S, 16);  T += __shfl_xor(T, 16);
            S += __shfl_xor(S, 32);  T += __shfl_xor(T, 32);
            if (blkl == 0)
                *(float2*)&part[t][rw][w][0] = make_float2(S, T);
        }
    }

    __syncthreads();

    // ---- combine wave partials: thread r finishes row r (r < 128) ----
    float entl = 0.0f;
    if (tid < 128) {
        const int c = tid >> 4, r16 = tid & 15;
        float S = 0.f, T = 0.f;
        #pragma unroll
        for (int ww = 0; ww < 8; ++ww) {
            S += part[c][r16][ww][0];
            T += part[c][r16][ww][1];
        }
        entl = __logf(S) - T / S;
    }
    #pragma unroll
    for (int msk = 1; msk <= 32; msk <<= 1) entl += __shfl_xor(entl, msk);
    if (lane == 0) entred[w] = entl;
    __syncthreads();
    if (tid == 0) {
        float b = 0.f;
        #pragma unroll
        for (int i = 0; i < 8; ++i) b += entred[i];
        blocksum[blockIdx.x] = b;
    }
}

__global__ __launch_bounds__(1024) void finalize(
    const float* __restrict__ blocksum, const float* __restrict__ m,
    const float* __restrict__ s2, float* __restrict__ out)
{
    __shared__ float xmp[8][128];
    __shared__ float xm[128];
    __shared__ double dred[16];
    __shared__ float redS[16], redT[16];
    const int tid  = threadIdx.x;
    const int lane = tid & 63;
    const int w    = tid >> 6;

    // intra partials (2048) in double
    double ds = (double)blocksum[tid] + (double)blocksum[tid + 1024];
    #pragma unroll
    for (int msk = 1; msk <= 32; msk <<= 1) ds += __shfl_xor(ds, msk);
    if (lane == 0) dred[w] = ds;

    // mean center: coalesced column sums
    {
        const int f = tid & 127, g = tid >> 7;
        const float* mp = m + (size_t)g * 32 * 128 + f;
        float cs = 0.f;
        #pragma unroll 8
        for (int k = 0; k < 32; ++k) cs += mp[(size_t)k * 128];
        xmp[g][f] = cs;
    }
    __syncthreads();
    if (tid < 128) {
        float s = 0.f;
        #pragma unroll
        for (int g = 0; g < 8; ++g) s += xmp[g][tid];
        xm[tid] = s * (1.0f / 256.0f);
    }
    __syncthreads();

    // per-center d2 (4 lanes per center)
    const int k = tid >> 2, q = tid & 3;
    float d2 = 0.f;
    {
        const float4* mr  = (const float4*)(m + (size_t)k * 128) + q * 8;
        const float4* xv4 = (const float4*)xm + q * 8;
        #pragma unroll
        for (int j = 0; j < 8; ++j) {
            float4 mv = mr[j], xv = xv4[j];
            float dx = xv.x - mv.x, dy = xv.y - mv.y,
                  dz = xv.z - mv.z, dw = xv.w - mv.w;
            d2 += dx*dx + dy*dy + dz*dz + dw*dw;
        }
    }
    d2 += __shfl_xor(d2, 1);
    d2 += __shfl_xor(d2, 2);
    float sv = s2[k];
    float rr = sqrtf(d2) / sv;
    float lg = -(rr * rr);
    float e  = (q == 0) ? __expf(lg) : 0.f;
    float S = e, T = (q == 0) ? lg * e : 0.f;
    #pragma unroll
    for (int msk = 1; msk <= 32; msk <<= 1) {
        S += __shfl_xor(S, msk);
        T += __shfl_xor(T, msk);
    }
    if (lane == 0) { redS[w] = S; redT[w] = T; }
    __syncthreads();
    if (tid == 0) {
        float Sa = 0.f, Ta = 0.f;
        double intra_d = 0.0;
        #pragma unroll
        for (int i = 0; i < 16; ++i) {
            Sa += redS[i]; Ta += redT[i]; intra_d += dred[i];
        }
        float inter = __logf(Sa) - Ta / Sa;
        float intra = (float)(intra_d / (double)N_ROWS);
        out[0] = intra - inter;   // LAMB = 1
        out[1] = intra;
        out[2] = inter;
    }
}

extern "C" void kernel_launch(void* const* d_in, const int* in_sizes, int n_in,
                              void* d_out, int out_size, void* d_ws, size_t ws_size,
                              hipStream_t stream) {
    const float* x  = (const float*)d_in[0];
    const float* m  = (const float*)d_in[1];
    const float* s1 = (const float*)d_in[2];
    const float* s2 = (const float*)d_in[3];
    float* out = (float*)d_out;

    char* ws = (char*)d_ws;
    unsigned short* mhi_g = (unsigned short*)ws;       // 65536 B
    float* p2_g     = (float*)(ws + 65536);            // 1 KiB
    float* blocksum = (float*)(ws + 65536 + 1024);     // 8 KiB (2048 f32)

    prep<<<dim3(32), dim3(256), 0, stream>>>(m, s1, mhi_g, p2_g);
    fused_main<<<dim3(2048), dim3(512), 0, stream>>>(x, mhi_g, p2_g, blocksum);
    finalize<<<dim3(1), dim3(1024), 0, stream>>>(blocksum, m, s2, out);
}

// Round 8
// 204.563 us; speedup vs baseline: 1.3585x; 1.3585x over previous
//
#include <hip/hip_runtime.h>
#include <hip/hip_bf16.h>

// LossUnsupervised v7 — LDS-shared bf16 x-frags (convert once per block).
// prep (32x256): m' = m/s1^2 -> bf16 A-frag order (ws); p2 = (1+|m|^2)/s1^2.
// fused_main (2048x256, 4 waves): block owns 128 rows (8 chunks of 16).
//   Per chunk: 256 threads load+convert x ONCE (bf16, n2 fused), ds_write
//   granule-swizzled (g ^= (g>>4)&7, both sides); each wave ds_read_b128
//   frags lane-linear and MFMAs against its stationary 64-center MB
//   (16 frags = 64 VGPR). Softmax partials (S,T; row max fixed at 0)
//   lane-local + 2 shfl_xor -> part LDS; combine after the loop.
//   T14: chunk t+1 loads issue before chunk t compute; 1 barrier/chunk.
// finalize (1x1024): blocksum reduce (double) + inter-center entropy.

#define N_ROWS 262144

typedef __attribute__((ext_vector_type(8))) short bf16x8;
typedef __attribute__((ext_vector_type(4))) float f32x4;
typedef __attribute__((ext_vector_type(4))) unsigned short u16x4;

__device__ __forceinline__ unsigned short bf16_rne(float x) {
    unsigned int u = __float_as_uint(x);
    u += 0x7FFFu + ((u >> 16) & 1u);
    return (unsigned short)(u >> 16);
}

__global__ __launch_bounds__(256) void prep(
    const float* __restrict__ m, const float* __restrict__ s1,
    unsigned short* __restrict__ mhi_g, float* __restrict__ p2_g)
{
    const int t    = threadIdx.x;
    const int lane = t & 63;
    const int k    = blockIdx.x * 8 + (t >> 5);   // center index
    const int f4   = t & 31;                      // float4 within row
    float4 v = reinterpret_cast<const float4*>(m)[k * 32 + f4];
    float pn = v.x*v.x + v.y*v.y + v.z*v.z + v.w*v.w;
    #pragma unroll
    for (int msk = 1; msk <= 16; msk <<= 1) pn += __shfl_xor(pn, msk);
    float sv  = s1[k];
    float isv = 1.0f / (sv * sv);
    if ((lane & 31) == 0) p2_g[k] = (1.0f + pn) * isv;   // (1+|m|^2)/s^2
    const int f0 = f4 << 2;
    const int c = k >> 4, n = k & 15, s = f0 >> 5, blk = (f0 >> 3) & 3, i0 = f0 & 7;
    const int elem = ((c * 4 + s) * 64 + blk * 16 + n) * 8 + i0;
    float xs[4] = {v.x * isv, v.y * isv, v.z * isv, v.w * isv};  // m' = m/s^2
    u16x4 hh;
    #pragma unroll
    for (int q = 0; q < 4; ++q) hh[q] = bf16_rne(xs[q]);
    *(u16x4*)(mhi_g + elem) = hh;
}

__global__ __launch_bounds__(256, 3) void fused_main(
    const float* __restrict__ x, const unsigned short* __restrict__ mhi_g,
    const float* __restrict__ p2_g, float* __restrict__ blocksum)
{
    __shared__ unsigned short xfrag[2][2048];   // dbuf, 256 granules x 8 bf16
    __shared__ float n2s[2][16];
    __shared__ float p2s[256];
    __shared__ float part[8][16][4][2];         // [chunk][row16][wave][S,T]
    __shared__ float entred[4];

    const int tid  = threadIdx.x;
    const int lane = tid & 63;
    const int w    = tid >> 6;        // wave 0..3: centers [64w, 64w+64)
    const int rw   = lane & 15;       // x-row within chunk (C col)
    const int blkl = lane >> 4;       // C row-group

    // staging role: thread t stages row sr, features sc*8..sc*8+8
    const int sr  = tid >> 4;         // row 0..15
    const int sc  = tid & 15;         // segment; note sc = ss*4 + sb
    const int gw0 = (sc >> 2) * 64 + (sc & 3) * 16 + sr;   // logical granule
    const int gw  = gw0 ^ ((gw0 >> 4) & 7);                // swizzled

    p2s[tid] = p2_g[tid];

    // stationary B: 4 center-tiles x 4 ksteps, 64 VGPR
    bf16x8 MB[16];
    #pragma unroll
    for (int tt = 0; tt < 4; ++tt)
        #pragma unroll
        for (int s = 0; s < 4; ++s)
            MB[tt*4+s] = *(const bf16x8*)(mhi_g + (((4*w + tt)*4 + s)*64 + lane)*8);

    const float* xrow = x + (size_t)(blockIdx.x * 128 + sr) * 128 + sc * 8;

    // ---- stage chunk 0 into buf 0 ----
    {
        float4 La = *(const float4*)xrow;
        float4 Lb = *(const float4*)(xrow + 4);
        float xs[8] = {La.x, La.y, La.z, La.w, Lb.x, Lb.y, Lb.z, Lb.w};
        float n2p = 0.f;
        unsigned hp[4];
        #pragma unroll
        for (int p = 0; p < 4; ++p) {
            float e = xs[2*p], o = xs[2*p+1];
            n2p = __builtin_fmaf(e, e, n2p);
            n2p = __builtin_fmaf(o, o, n2p);
            __hip_bfloat162 hv = __float22bfloat162_rn(make_float2(e, o));
            hp[p] = *reinterpret_cast<unsigned*>(&hv);
        }
        *(bf16x8*)&xfrag[0][gw * 8] = *reinterpret_cast<bf16x8*>(hp);
        #pragma unroll
        for (int msk = 1; msk <= 8; msk <<= 1) n2p += __shfl_xor(n2p, msk);
        if (sc == 0) n2s[0][sr] = n2p;
    }
    __syncthreads();

    for (int t = 0; t < 8; ++t) {
        const int cur = t & 1;

        // T14: issue next chunk's loads first (hidden under MFMA+epilogue)
        float4 Na, Nb;
        if (t < 7) {
            const float* p = xrow + (size_t)(t + 1) * 2048;
            Na = *(const float4*)p;
            Nb = *(const float4*)(p + 4);
        }

        // ---- compute chunk t from buf[cur] ----
        f32x4 acc[4];
        #pragma unroll
        for (int tt = 0; tt < 4; ++tt) acc[tt] = f32x4{0.f, 0.f, 0.f, 0.f};
        #pragma unroll
        for (int s = 0; s < 4; ++s) {
            int gr = s * 64 + lane;
            gr ^= (gr >> 4) & 7;
            bf16x8 xf = *(const bf16x8*)&xfrag[cur][gr * 8];
            #pragma unroll
            for (int tt = 0; tt < 4; ++tt)
                acc[tt] = __builtin_amdgcn_mfma_f32_16x16x32_bf16(MB[tt*4+s], xf, acc[tt], 0, 0, 0);
        }

        // ---- epilogue: lane-local softmax partials over 64 centers ----
        float nn = n2s[cur][rw];
        float ar = 2.0f * __frsqrt_rn(fmaxf(nn, 1e-24f));
        float S = 0.f, T = 0.f;
        #pragma unroll
        for (int tt = 0; tt < 4; ++tt) {
            f32x4 p2v = *(const f32x4*)&p2s[(4*w + tt)*16 + blkl*4];
            #pragma unroll
            for (int r = 0; r < 4; ++r) {
                float l = fminf(__builtin_fmaf(ar, acc[tt][r], -p2v[r]), 0.0f);
                float e = __expf(l);
                S += e;
                T = __builtin_fmaf(l, e, T);
            }
        }
        S += __shfl_xor(S, 16);  T += __shfl_xor(T, 16);
        S += __shfl_xor(S, 32);  T += __shfl_xor(T, 32);
        if (blkl == 0)
            *(float2*)&part[t][rw][w][0] = make_float2(S, T);

        // ---- stage chunk t+1 into buf[cur^1] (write-late) ----
        if (t < 7) {
            float xs[8] = {Na.x, Na.y, Na.z, Na.w, Nb.x, Nb.y, Nb.z, Nb.w};
            float n2p = 0.f;
            unsigned hp[4];
            #pragma unroll
            for (int p = 0; p < 4; ++p) {
                float e = xs[2*p], o = xs[2*p+1];
                n2p = __builtin_fmaf(e, e, n2p);
                n2p = __builtin_fmaf(o, o, n2p);
                __hip_bfloat162 hv = __float22bfloat162_rn(make_float2(e, o));
                hp[p] = *reinterpret_cast<unsigned*>(&hv);
            }
            *(bf16x8*)&xfrag[cur ^ 1][gw * 8] = *reinterpret_cast<bf16x8*>(hp);
            #pragma unroll
            for (int msk = 1; msk <= 8; msk <<= 1) n2p += __shfl_xor(n2p, msk);
            if (sc == 0) n2s[cur ^ 1][sr] = n2p;
        }
        __syncthreads();
    }

    // ---- combine wave partials: thread r finishes row r (r < 128) ----
    float entl = 0.0f;
    if (tid < 128) {
        const int c = tid >> 4, r16 = tid & 15;
        float S = 0.f, T = 0.f;
        #pragma unroll
        for (int ww = 0; ww < 4; ++ww) {
            S += part[c][r16][ww][0];
            T += part[c][r16][ww][1];
        }
        entl = __logf(S) - T / S;
    }
    #pragma unroll
    for (int msk = 1; msk <= 32; msk <<= 1) entl += __shfl_xor(entl, msk);
    if (lane == 0) entred[w] = entl;
    __syncthreads();
    if (tid == 0)
        blocksum[blockIdx.x] = entred[0] + entred[1] + entred[2] + entred[3];
}

__global__ __launch_bounds__(1024) void finalize(
    const float* __restrict__ blocksum, const float* __restrict__ m,
    const float* __restrict__ s2, float* __restrict__ out)
{
    __shared__ float xmp[8][128];
    __shared__ float xm[128];
    __shared__ double dred[16];
    __shared__ float redS[16], redT[16];
    const int tid  = threadIdx.x;
    const int lane = tid & 63;
    const int w    = tid >> 6;

    // intra partials (2048) in double
    double ds = (double)blocksum[tid] + (double)blocksum[tid + 1024];
    #pragma unroll
    for (int msk = 1; msk <= 32; msk <<= 1) ds += __shfl_xor(ds, msk);
    if (lane == 0) dred[w] = ds;

    // mean center: coalesced column sums
    {
        const int f = tid & 127, g = tid >> 7;
        const float* mp = m + (size_t)g * 32 * 128 + f;
        float cs = 0.f;
        #pragma unroll 8
        for (int k = 0; k < 32; ++k) cs += mp[(size_t)k * 128];
        xmp[g][f] = cs;
    }
    __syncthreads();
    if (tid < 128) {
        float s = 0.f;
        #pragma unroll
        for (int g = 0; g < 8; ++g) s += xmp[g][tid];
        xm[tid] = s * (1.0f / 256.0f);
    }
    __syncthreads();

    // per-center d2 (4 lanes per center)
    const int k = tid >> 2, q = tid & 3;
    float d2 = 0.f;
    {
        const float4* mr  = (const float4*)(m + (size_t)k * 128) + q * 8;
        const float4* xv4 = (const float4*)xm + q * 8;
        #pragma unroll
        for (int j = 0; j < 8; ++j) {
            float4 mv = mr[j], xv = xv4[j];
            float dx = xv.x - mv.x, dy = xv.y - mv.y,
                  dz = xv.z - mv.z, dw = xv.w - mv.w;
            d2 += dx*dx + dy*dy + dz*dz + dw*dw;
        }
    }
    d2 += __shfl_xor(d2, 1);
    d2 += __shfl_xor(d2, 2);
    float sv = s2[k];
    float rr = sqrtf(d2) / sv;
    float lg = -(rr * rr);
    float e  = (q == 0) ? __expf(lg) : 0.f;
    float S = e, T = (q == 0) ? lg * e : 0.f;
    #pragma unroll
    for (int msk = 1; msk <= 32; msk <<= 1) {
        S += __shfl_xor(S, msk);
        T += __shfl_xor(T, msk);
    }
    if (lane == 0) { redS[w] = S; redT[w] = T; }
    __syncthreads();
    if (tid == 0) {
        float Sa = 0.f, Ta = 0.f;
        double intra_d = 0.0;
        #pragma unroll
        for (int i = 0; i < 16; ++i) {
            Sa += redS[i]; Ta += redT[i]; intra_d += dred[i];
        }
        float inter = __logf(Sa) - Ta / Sa;
        float intra = (float)(intra_d / (double)N_ROWS);
        out[0] = intra - inter;   // LAMB = 1
        out[1] = intra;
        out[2] = inter;
    }
}

extern "C" void kernel_launch(void* const* d_in, const int* in_sizes, int n_in,
                              void* d_out, int out_size, void* d_ws, size_t ws_size,
                              hipStream_t stream) {
    const float* x  = (const float*)d_in[0];
    const float* m  = (const float*)d_in[1];
    const float* s1 = (const float*)d_in[2];
    const float* s2 = (const float*)d_in[3];
    float* out = (float*)d_out;

    char* ws = (char*)d_ws;
    unsigned short* mhi_g = (unsigned short*)ws;       // 65536 B
    float* p2_g     = (float*)(ws + 65536);            // 1 KiB
    float* blocksum = (float*)(ws + 65536 + 1024);     // 8 KiB (2048 f32)

    prep<<<dim3(32), dim3(256), 0, stream>>>(m, s1, mhi_g, p2_g);
    fused_main<<<dim3(2048), dim3(256), 0, stream>>>(x, mhi_g, p2_g, blocksum);
    finalize<<<dim3(1), dim3(1024), 0, stream>>>(blocksum, m, s2, out);
}